// Round 13
// baseline (174.690 us; speedup 1.0000x reference)
//
#include <hip/hip_runtime.h>
#include <hip/hip_bf16.h>

#define B_  2
#define S_  2048
#define H_  1024
#define NH_ 16
#define HD_ 64
#define NTOK (B_*S_)   // 4096

typedef __attribute__((ext_vector_type(8)))  short bf16x8;
typedef __attribute__((ext_vector_type(4)))  float f32x4;
typedef __attribute__((ext_vector_type(16))) float f32x16;

#define SC2 0.18033688011112042f   // (1/sqrt(64)) * log2(e)
#define AVGINV (1.f/((float)NH_*(float)S_))

static __device__ __forceinline__ ushort f2bf(float f) {
    __hip_bfloat16 h = __float2bfloat16(f);
    return *reinterpret_cast<ushort*>(&h);
}
static __device__ __forceinline__ uint cvt_pk_bf16(float lo, float hi) {
    uint r;
    asm("v_cvt_pk_bf16_f32 %0, %1, %2" : "=v"(r) : "v"(lo), "v"(hi));
    return r;
}

static __device__ __forceinline__ void gload_lds16(const void* g, void* l) {
    __builtin_amdgcn_global_load_lds(
        (const __attribute__((address_space(1))) void*)g,
        (__attribute__((address_space(3))) void*)l,
        16, 0, 0);
}

// ---------------------------------------------------------------
// prep: all f32->bf16 converts + avg_out zero in ONE launch.
// ---------------------------------------------------------------
struct PrepArgs {
    const float* src[5];   // x, Wq, Wk, Wv, Wo
    ushort*      dst[5];
    float*       zero;     // avg_out
};

static __device__ __forceinline__ void conv8(const float* __restrict__ s,
                                             ushort* __restrict__ d, int i)
{
    const float4 a = reinterpret_cast<const float4*>(s)[2*i + 0];
    const float4 b = reinterpret_cast<const float4*>(s)[2*i + 1];
    ushort u[8];
    u[0] = f2bf(a.x); u[1] = f2bf(a.y); u[2] = f2bf(a.z); u[3] = f2bf(a.w);
    u[4] = f2bf(b.x); u[5] = f2bf(b.y); u[6] = f2bf(b.z); u[7] = f2bf(b.w);
    reinterpret_cast<uint4*>(d)[i] = *reinterpret_cast<uint4*>(u);
}

__global__ __launch_bounds__(256) void prep(PrepArgs a)
{
    int bid = blockIdx.x;
    const int t = threadIdx.x;
    if (bid < 2048) {
        conv8(a.src[0], a.dst[0], bid*256 + t);
        return;
    }
    bid -= 2048;
    if (bid < 2048) {
        const int wi = 1 + (bid >> 9);
        const int i  = (bid & 511)*256 + t;
        conv8(a.src[wi], a.dst[wi], i);
        return;
    }
    bid -= 2048;
    const int i = bid*256 + t;
    if (i < NTOK) a.zero[i] = 0.f;
}

// ---------------------------------------------------------------
// V [tok][H] bf16 -> Vt [(b*NH+h)][d][s] bf16
// ---------------------------------------------------------------
__global__ __launch_bounds__(256) void transpose_v(
    const ushort* __restrict__ Vb, ushort* __restrict__ Vt)
{
    __shared__ ushort T[64][72];
    const int t  = threadIdx.x;
    const int b  = blockIdx.z;
    const int h  = blockIdx.y;
    const int s0 = blockIdx.x * 64;
    const int r  = t >> 2;
    const int c0 = (t & 3) * 16;

    const ushort* src = Vb + (size_t)(b*S_ + s0 + r)*H_ + h*HD_ + c0;
    *reinterpret_cast<uint4*>(&T[r][c0])     = *reinterpret_cast<const uint4*>(src);
    *reinterpret_cast<uint4*>(&T[r][c0 + 8]) = *reinterpret_cast<const uint4*>(src + 8);
    __syncthreads();

    const int d = r;
    ushort tmp[16];
#pragma unroll
    for (int k = 0; k < 16; ++k) tmp[k] = T[c0 + k][d];
    ushort* dst = Vt + ((size_t)((b*NH_ + h)*HD_ + d))*S_ + s0 + c0;
    *reinterpret_cast<uint4*>(dst)     = *reinterpret_cast<uint4*>(&tmp[0]);
    *reinterpret_cast<uint4*>(dst + 8) = *reinterpret_cast<uint4*>(&tmp[8]);
}

// ---------------------------------------------------------------
// MFMA GEMM (QKV, fused over z): Y = (A @ W^T + bias) * scale, bf16 out
// ---------------------------------------------------------------
struct GemmArgs {
    const ushort* W[3];
    const float*  bias[3];
    void*         Y[3];
    float         scale[3];
};

__global__ __launch_bounds__(256) void gemm_qkv(
    const ushort* __restrict__ A, GemmArgs args, int M, int N, int K)
{
    constexpr int MREP = 4;
    constexpr int BM = MREP * 32;
    __shared__ __align__(16) ushort As[BM * 64];
    __shared__ __align__(16) ushort Bs[128 * 64];

    const int z = blockIdx.z;
    const ushort* __restrict__ W   = args.W[z];
    const float*  __restrict__ bia = args.bias[z];
    const float sc = args.scale[z];

    const int t  = threadIdx.x;
    const int w  = t >> 6;
    const int l  = t & 63;
    const int lq = l >> 4;
    const int ln = l & 15;
    const int wr = w >> 1;
    const int wc = w & 1;
    const int m0 = blockIdx.x * BM;
    const int n0 = blockIdx.y * 128;
    const int srow = l >> 3;
    const int scol = (l & 7) * 8;

    f32x4 acc[MREP][4];
#pragma unroll
    for (int m = 0; m < MREP; ++m)
#pragma unroll
        for (int n = 0; n < 4; ++n) acc[m][n] = f32x4{0.f, 0.f, 0.f, 0.f};

    for (int k0 = 0; k0 < K; k0 += 64) {
        __syncthreads();
#pragma unroll
        for (int i = 0; i < BM/32; ++i) {
            const int rb = i*32 + w*8;
            gload_lds16(A + (size_t)(m0 + rb + srow)*K + k0 + scol, &As[rb*64]);
        }
#pragma unroll
        for (int i = 0; i < 4; ++i) {
            const int rb = i*32 + w*8;
            gload_lds16(W + (size_t)(n0 + rb + srow)*K + k0 + scol, &Bs[rb*64]);
        }
        __syncthreads();
#pragma unroll
        for (int ks = 0; ks < 2; ++ks) {
            bf16x8 bfr[4];
#pragma unroll
            for (int n = 0; n < 4; ++n)
                bfr[n] = *reinterpret_cast<const bf16x8*>(&Bs[(wc*64 + n*16 + ln)*64 + ks*32 + lq*8]);
#pragma unroll
            for (int m = 0; m < MREP; ++m) {
                const bf16x8 afr = *reinterpret_cast<const bf16x8*>(&As[(wr*MREP*16 + m*16 + ln)*64 + ks*32 + lq*8]);
#pragma unroll
                for (int n = 0; n < 4; ++n)
                    acc[m][n] = __builtin_amdgcn_mfma_f32_16x16x32_bf16(afr, bfr[n], acc[m][n], 0, 0, 0);
            }
        }
    }

    float bv[4];
#pragma unroll
    for (int n = 0; n < 4; ++n) bv[n] = bia[n0 + wc*64 + n*16 + ln];

    ushort* Y = (ushort*)args.Y[z];
#pragma unroll
    for (int m = 0; m < MREP; ++m) {
#pragma unroll
        for (int r = 0; r < 4; ++r) {
            const size_t row = (size_t)(m0 + wr*MREP*16 + m*16 + lq*4 + r);
#pragma unroll
            for (int n = 0; n < 4; ++n) {
                const int col = n0 + wc*64 + n*16 + ln;
                Y[row*N + col] = f2bf((acc[m][n][r] + bv[n]) * sc);
            }
        }
    }
}

// ---------------------------------------------------------------
// attn_pv (round 13): 32x32x16 MFMA, swapped QK, IN-REGISTER P via
// cvt_pk + v_permlane32_swap (T12) — no P LDS round-trip.
// Wave owns 32 q. Per tile (64 keys): 8 QK + 8 PV + 4 lsum MFMAs,
// 16 b128 LDS reads, 0 LDS writes. K/V dbuf, one barrier per tile,
// XCD swizzle, pre-scaled Q, deferred normalization.
// C/D layout (verified): col = lane&31, row = (r&3)+8*(r>>2)+4*(lane>>5).
// A/B frag: row/col = lane&31, kelem = (lane>>5)*8 + j.
// ---------------------------------------------------------------
__global__ __launch_bounds__(256) void attn_pv(
    const ushort* __restrict__ Qb, const ushort* __restrict__ Kb,
    const ushort* __restrict__ Vtg, ushort* __restrict__ ctx,
    float* __restrict__ il2_g)
{
    __shared__ __align__(16) ushort Ks0[64*64];
    __shared__ __align__(16) ushort Ks1[64*64];
    __shared__ __align__(16) ushort Vs0[64*64];
    __shared__ __align__(16) ushort Vs1[64*64];

    const int id  = blockIdx.x;
    const int qt_ = (id >> 3) & 15;
    const int bh  = (id & 7) + ((id >> 7) << 3);
    const int b   = bh >> 4;
    const int h   = bh & 15;
    const int q0  = qt_ * 128;

    const int t  = threadIdx.x;
    const int w  = t >> 6;
    const int l  = t & 63;
    const int c  = l & 31;      // q column (QK) / d column (PV) / key row (A of QK)
    const int hi = l >> 5;
    const int c7 = c & 7;

    // Q B-fragments: Q[q = q0 + w*32 + c][d = step*16 + hi*8 + j], pre-scaled
    bf16x8 qf[4];
    {
        const ushort* qrow = Qb + ((size_t)(b*S_ + q0 + w*32 + c))*H_ + h*HD_ + hi*8;
#pragma unroll
        for (int s = 0; s < 4; ++s)
            qf[s] = *reinterpret_cast<const bf16x8*>(qrow + s*16);
    }

    bf16x8 onesb;
#pragma unroll
    for (int j = 0; j < 8; ++j) onesb[j] = (short)0x3F80;

    f32x16 lsacc = {};
    f32x16 oacc[2] = {{}, {}};

    // staging: thread covers chunks {t, 256+t}; swizzled source (T21)
    size_t koff[2], voff[2];
    int    dsto[2];
#pragma unroll
    for (int i = 0; i < 2; ++i) {
        const int chunk = i*256 + t;
        const int row   = chunk >> 3;
        const int c8    = (chunk & 7) ^ (row & 7);
        koff[i] = (size_t)(b*S_ + row)*H_ + h*HD_ + c8*8;
        voff[i] = ((size_t)((b*NH_ + h)*HD_ + row))*S_ + c8*8;
        dsto[i] = chunk*8;
    }

    auto tile_body = [&](const ushort* __restrict__ ksb, const ushort* __restrict__ vsb,
                         int pre_kt, bool do_pre,
                         ushort* __restrict__ kdst, ushort* __restrict__ vdst) {
        if (do_pre) {
#pragma unroll
            for (int i = 0; i < 2; ++i) {
                gload_lds16(Kb + koff[i] + (size_t)pre_kt*H_, &kdst[dsto[i]]);
                gload_lds16(Vtg + voff[i] + pre_kt, &vdst[dsto[i]]);
            }
        }

#pragma unroll
        for (int sub = 0; sub < 2; ++sub) {
            // ---- swapped QK: D[key=crow(r,hi)][q=c] over 32 keys ----
            f32x16 sacc;
            {
                const bf16x8 kb = *reinterpret_cast<const bf16x8*>(
                    &ksb[(sub*32 + c)*64 + ((hi ^ c7) * 8)]);
                f32x16 zed = {};
                sacc = __builtin_amdgcn_mfma_f32_32x32x16_bf16(kb, qf[0], zed, 0, 0, 0);
            }
#pragma unroll
            for (int s = 1; s < 4; ++s) {
                const bf16x8 kb = *reinterpret_cast<const bf16x8*>(
                    &ksb[(sub*32 + c)*64 + (((s*2 + hi) ^ c7) * 8)]);
                sacc = __builtin_amdgcn_mfma_f32_32x32x16_bf16(kb, qf[s], sacc, 0, 0, 0);
            }

            // ---- exp ----
            float e[16];
#pragma unroll
            for (int r = 0; r < 16; ++r) e[r] = exp2f(sacc[r]);

            // ---- in-register P: per 16-key window, cvt_pk + permlane32_swap ----
#pragma unroll
            for (int win = 0; win < 2; ++win) {
                const int e0 = win*8;
                uint x = cvt_pk_bf16(e[e0+0], e[e0+1]);
                uint y = cvt_pk_bf16(e[e0+2], e[e0+3]);
                uint z = cvt_pk_bf16(e[e0+4], e[e0+5]);
                uint wv = cvt_pk_bf16(e[e0+6], e[e0+7]);
                // swap upper half of first with lower half of second:
                // x' = A-frag uint0 (keys hi*8+{0,1}), z' = uint2 (keys hi*8+{4,5})
                asm("v_permlane32_swap_b32 %0, %1" : "+v"(x), "+v"(z));
                asm("v_permlane32_swap_b32 %0, %1" : "+v"(y), "+v"(wv));
                uint pau[4] = {x, y, z, wv};
                const bf16x8 pa = *reinterpret_cast<const bf16x8*>(pau);

                // lsum: D[q=crow][*] += sum_k P — same row layout as oacc
                lsacc = __builtin_amdgcn_mfma_f32_32x32x16_bf16(pa, onesb, lsacc, 0, 0, 0);

                // PV: O[q=crow(r,hi)][d = dsub*32 + c]
#pragma unroll
                for (int dsub = 0; dsub < 2; ++dsub) {
                    const bf16x8 vb = *reinterpret_cast<const bf16x8*>(
                        &vsb[(dsub*32 + c)*64 + (((sub*4 + win*2 + hi) ^ c7) * 8)]);
                    oacc[dsub] = __builtin_amdgcn_mfma_f32_32x32x16_bf16(pa, vb, oacc[dsub], 0, 0, 0);
                }
            }
        }

        __syncthreads();   // drains own vmcnt -> prefetched bufs landed
    };

    // prologue: stage tile 0 into buf 0
#pragma unroll
    for (int i = 0; i < 2; ++i) {
        gload_lds16(Kb + koff[i], &Ks0[dsto[i]]);
        gload_lds16(Vtg + voff[i], &Vs0[dsto[i]]);
    }
    __syncthreads();

    for (int kt = 0; kt < S_; kt += 128) {
        tile_body(Ks0, Vs0, kt + 64, true, Ks1, Vs1);
        tile_body(Ks1, Vs1, kt + 128, kt + 128 < S_, Ks0, Vs0);
    }

    // epilogue: q = q0 + w*32 + crow(r,hi); lsacc rows align with oacc rows
    if (c == 0) {
#pragma unroll
        for (int r = 0; r < 16; ++r) {
            const int qrow = (r & 3) + 8*(r >> 2) + 4*hi;
            il2_g[(size_t)(b*NH_ + h)*S_ + q0 + w*32 + qrow] = -__log2f(lsacc[r]);
        }
    }

#pragma unroll
    for (int r = 0; r < 16; ++r) {
        const int qrow = (r & 3) + 8*(r >> 2) + 4*hi;
        const float iv = 1.f / lsacc[r];
        ushort* crow_p = ctx + ((size_t)(b*S_ + q0 + w*32 + qrow))*H_ + h*HD_ + c;
        crow_p[0]  = f2bf(oacc[0][r] * iv);
        crow_p[32] = f2bf(oacc[1][r] * iv);
    }
}

// ---------------------------------------------------------------
// fused colsum + out-projection (unchanged from round 12).
// ---------------------------------------------------------------
struct FusedArgs {
    const ushort* Qb; const ushort* Kb;
    const float*  il2; float* avg_out;
    const ushort* A;  const ushort* W;
    const float*  bias; float* Y;
};

__global__ __launch_bounds__(256) void colsum_outproj(FusedArgs fa)
{
    __shared__ __align__(16) char smem[32768];
    const int id = blockIdx.x;
    const int t  = threadIdx.x;
    const int w  = t >> 6;
    const int l  = t & 63;
    const int lq = l >> 4;
    const int ln = l & 15;
    const int ln7 = ln & 7;
    const f32x4 ZED = f32x4{0.f, 0.f, 0.f, 0.f};

    if (id < 1024) {
        ushort* KsT = (ushort*)smem;
        ushort* Qs0 = (ushort*)(smem + 8192);
        ushort* Qs1 = (ushort*)(smem + 16384);
        float*  iv  = (float*)(smem + 24576);

        const int kt_ = (id >> 3) & 31;
        const int bh  = (id & 7) + ((id >> 8) << 3);
        const int b   = bh >> 4;
        const int h   = bh & 15;
        const int k0  = kt_ * 64;

        int crow_[2], cc8[2], dsto[2];
#pragma unroll
        for (int i = 0; i < 2; ++i) {
            const int chunk = i*256 + t;
            crow_[i] = chunk >> 3;
            cc8[i]   = (chunk & 7) ^ (crow_[i] & 7);
            dsto[i]  = chunk*8;
        }

#pragma unroll
        for (int i = 0; i < 2; ++i) {
            gload_lds16(fa.Kb + (size_t)(b*S_ + k0 + crow_[i])*H_ + h*HD_ + cc8[i]*8, &KsT[dsto[i]]);
            gload_lds16(fa.il2 + (size_t)bh*S_ + (i*256 + t)*4, &iv[(i*256 + t)*4]);
            gload_lds16(fa.Qb + (size_t)(b*S_ + crow_[i])*H_ + h*HD_ + cc8[i]*8, &Qs0[dsto[i]]);
        }
        __syncthreads();

        bf16x8 kf[2];
#pragma unroll
        for (int ks = 0; ks < 2; ++ks)
            kf[ks] = *reinterpret_cast<const bf16x8*>(
                &KsT[(w*16 + ln)*64 + (((ks*4 + lq) ^ ln7) * 8)]);

        float cs4[4] = {0.f, 0.f, 0.f, 0.f};

        for (int qt = 0; qt < S_; qt += 128) {
#pragma unroll
            for (int i = 0; i < 2; ++i)
                gload_lds16(fa.Qb + (size_t)(b*S_ + qt + 64 + crow_[i])*H_ + h*HD_ + cc8[i]*8,
                            &Qs1[dsto[i]]);
#pragma unroll
            for (int cc = 0; cc < 4; ++cc) {
                const bf16x8 a0 = *reinterpret_cast<const bf16x8*>(
                    &Qs0[(cc*16 + ln)*64 + ((lq ^ ln7) * 8)]);
                const bf16x8 a1 = *reinterpret_cast<const bf16x8*>(
                    &Qs0[(cc*16 + ln)*64 + (((4 + lq) ^ ln7) * 8)]);
                f32x4 sacc = __builtin_amdgcn_mfma_f32_16x16x32_bf16(a0, kf[0], ZED, 0, 0, 0);
                sacc = __builtin_amdgcn_mfma_f32_16x16x32_bf16(a1, kf[1], sacc, 0, 0, 0);
                const f32x4 iv4 = *reinterpret_cast<const f32x4*>(&iv[qt + cc*16 + lq*4]);
#pragma unroll
                for (int r = 0; r < 4; ++r)
                    cs4[r] += exp2f(sacc[r] + iv4[r]);
            }
            __syncthreads();

            if (qt + 128 < S_) {
#pragma unroll
                for (int i = 0; i < 2; ++i)
                    gload_lds16(fa.Qb + (size_t)(b*S_ + qt + 128 + crow_[i])*H_ + h*HD_ + cc8[i]*8,
                                &Qs0[dsto[i]]);
            }
#pragma unroll
            for (int cc = 0; cc < 4; ++cc) {
                const bf16x8 a0 = *reinterpret_cast<const bf16x8*>(
                    &Qs1[(cc*16 + ln)*64 + ((lq ^ ln7) * 8)]);
                const bf16x8 a1 = *reinterpret_cast<const bf16x8*>(
                    &Qs1[(cc*16 + ln)*64 + (((4 + lq) ^ ln7) * 8)]);
                f32x4 sacc = __builtin_amdgcn_mfma_f32_16x16x32_bf16(a0, kf[0], ZED, 0, 0, 0);
                sacc = __builtin_amdgcn_mfma_f32_16x16x32_bf16(a1, kf[1], sacc, 0, 0, 0);
                const f32x4 iv4 = *reinterpret_cast<const f32x4*>(&iv[qt + 64 + cc*16 + lq*4]);
#pragma unroll
                for (int r = 0; r < 4; ++r)
                    cs4[r] += exp2f(sacc[r] + iv4[r]);
            }
            __syncthreads();
        }

        float cs = (cs4[0] + cs4[1]) + (cs4[2] + cs4[3]);
        cs += __shfl_xor(cs, 16);
        cs += __shfl_xor(cs, 32);
        if (l < 16)
            atomicAdd(&fa.avg_out[(size_t)b*S_ + k0 + w*16 + l], cs * AVGINV);
    } else {
        ushort* As = (ushort*)smem;
        ushort* Bs = (ushort*)(smem + 8192);

        const int g  = id - 1024;
        const int m0 = (g & 63) * 64;
        const int n0 = (g >> 6) * 128;
        const int wr = w >> 1;
        const int wc = w & 1;
        const int srow = l >> 3;
        const int scol = (l & 7) * 8;

        f32x4 acc[2][4];
#pragma unroll
        for (int m = 0; m < 2; ++m)
#pragma unroll
            for (int n = 0; n < 4; ++n) acc[m][n] = ZED;

        for (int k0 = 0; k0 < H_; k0 += 64) {
            __syncthreads();
#pragma unroll
            for (int i = 0; i < 2; ++i) {
                const int rb = i*32 + w*8;
                gload_lds16(fa.A + (size_t)(m0 + rb + srow)*H_ + k0 + scol, &As[rb*64]);
            }
#pragma unroll
            for (int i = 0; i < 4; ++i) {
                const int rb = i*32 + w*8;
                gload_lds16(fa.W + (size_t)(n0 + rb + srow)*H_ + k0 + scol, &Bs[rb*64]);
            }
            __syncthreads();
#pragma unroll
            for (int ks = 0; ks < 2; ++ks) {
                bf16x8 bfr[4];
#pragma unroll
                for (int n = 0; n < 4; ++n)
                    bfr[n] = *reinterpret_cast<const bf16x8*>(&Bs[(wc*64 + n*16 + ln)*64 + ks*32 + lq*8]);
#pragma unroll
                for (int m = 0; m < 2; ++m) {
                    const bf16x8 afr = *reinterpret_cast<const bf16x8*>(&As[(wr*32 + m*16 + ln)*64 + ks*32 + lq*8]);
#pragma unroll
                    for (int n = 0; n < 4; ++n)
                        acc[m][n] = __builtin_amdgcn_mfma_f32_16x16x32_bf16(afr, bfr[n], acc[m][n], 0, 0, 0);
                }
            }
        }

        float bv[4];
#pragma unroll
        for (int n = 0; n < 4; ++n) bv[n] = fa.bias[n0 + wc*64 + n*16 + ln];

#pragma unroll
        for (int m = 0; m < 2; ++m) {
#pragma unroll
            for (int r = 0; r < 4; ++r) {
                const size_t row = (size_t)(m0 + wr*32 + m*16 + lq*4 + r);
#pragma unroll
                for (int n = 0; n < 4; ++n) {
                    const int col = n0 + wc*64 + n*16 + ln;
                    fa.Y[row*H_ + col] = acc[m][n][r] + bv[n];
                }
            }
        }
    }
}

extern "C" void kernel_launch(void* const* d_in, const int* in_sizes, int n_in,
                              void* d_out, int out_size, void* d_ws, size_t ws_size,
                              hipStream_t stream)
{
    const float* x  = (const float*)d_in[0];
    const float* Wq = (const float*)d_in[1];
    const float* bq = (const float*)d_in[2];
    const float* Wk = (const float*)d_in[3];
    const float* bk = (const float*)d_in[4];
    const float* Wv = (const float*)d_in[5];
    const float* bv = (const float*)d_in[6];
    const float* Wo = (const float*)d_in[7];
    const float* bo = (const float*)d_in[8];

    float* out     = (float*)d_out;
    float* avg_out = out + (size_t)NTOK * H_;

    char* ws = (char*)d_ws;
    const size_t mat  = (size_t)NTOK * H_ * sizeof(ushort);   // 8 MB
    const size_t wmat = (size_t)H_ * H_ * sizeof(ushort);     // 2 MB
    ushort* xb   = (ushort*)(ws);                  // also ctx (x dead after projections)
    ushort* Qb   = (ushort*)(ws + mat);
    ushort* Kb   = (ushort*)(ws + 2*mat);
    ushort* Vb   = (ushort*)(ws + 3*mat);
    ushort* Vtg  = (ushort*)(ws + 4*mat);          // V^T [(b,h)][d][s]
    ushort* Wqb  = (ushort*)(ws + 5*mat);
    ushort* Wkb  = (ushort*)(ws + 5*mat + wmat);
    ushort* Wvb  = (ushort*)(ws + 5*mat + 2*wmat);
    ushort* Wob  = (ushort*)(ws + 5*mat + 3*wmat);
    float*  il2  = (float*)(ws + 5*mat + 4*wmat);              // 256 KB
    ushort* ctxb = xb;

    const dim3 blk(256);

    {
        PrepArgs pa;
        pa.src[0] = x;  pa.dst[0] = xb;
        pa.src[1] = Wq; pa.dst[1] = Wqb;
        pa.src[2] = Wk; pa.dst[2] = Wkb;
        pa.src[3] = Wv; pa.dst[3] = Wvb;
        pa.src[4] = Wo; pa.dst[4] = Wob;
        pa.zero = avg_out;
        prep<<<dim3(4112), blk, 0, stream>>>(pa);
    }

    {
        GemmArgs ga;
        ga.W[0] = Wqb; ga.W[1] = Wkb; ga.W[2] = Wvb;
        ga.bias[0] = bq; ga.bias[1] = bk; ga.bias[2] = bv;
        ga.Y[0] = Qb; ga.Y[1] = Kb; ga.Y[2] = Vb;
        ga.scale[0] = SC2; ga.scale[1] = 1.f; ga.scale[2] = 1.f;
        gemm_qkv<<<dim3(NTOK/128, H_/128, 3), blk, 0, stream>>>(xb, ga, NTOK, H_, H_);
    }

    transpose_v<<<dim3(S_/64, NH_, B_), blk, 0, stream>>>(Vb, Vtg);

    attn_pv<<<dim3(512), blk, 0, stream>>>(Qb, Kb, Vtg, ctxb, il2);

    {
        FusedArgs fa;
        fa.Qb = Qb; fa.Kb = Kb; fa.il2 = il2; fa.avg_out = avg_out;
        fa.A = ctxb; fa.W = Wob; fa.bias = bo; fa.Y = out;
        colsum_outproj<<<dim3(1536), blk, 0, stream>>>(fa);
    }
}

// Round 14
// 167.103 us; speedup vs baseline: 1.0454x; 1.0454x over previous
//
#include <hip/hip_runtime.h>
#include <hip/hip_bf16.h>

#define B_  2
#define S_  2048
#define H_  1024
#define NH_ 16
#define HD_ 64
#define NTOK (B_*S_)   // 4096

typedef __attribute__((ext_vector_type(8))) short bf16x8;
typedef __attribute__((ext_vector_type(4))) float f32x4;

#define SC2 0.18033688011112042f   // (1/sqrt(64)) * log2(e)
#define AVGINV (1.f/((float)NH_*(float)S_))

static __device__ __forceinline__ ushort f2bf(float f) {
    __hip_bfloat16 h = __float2bfloat16(f);
    return *reinterpret_cast<ushort*>(&h);
}
static __device__ __forceinline__ uint cvt_pk_bf16(float lo, float hi) {
    uint r;
    asm("v_cvt_pk_bf16_f32 %0, %1, %2" : "=v"(r) : "v"(lo), "v"(hi));
    return r;
}

static __device__ __forceinline__ void gload_lds16(const void* g, void* l) {
    __builtin_amdgcn_global_load_lds(
        (const __attribute__((address_space(1))) void*)g,
        (__attribute__((address_space(3))) void*)l,
        16, 0, 0);
}

// ---------------------------------------------------------------
// prep: all f32->bf16 converts + avg_out zero in ONE launch.
// ---------------------------------------------------------------
struct PrepArgs {
    const float* src[5];   // x, Wq, Wk, Wv, Wo
    ushort*      dst[5];
    float*       zero;     // avg_out
};

static __device__ __forceinline__ void conv8(const float* __restrict__ s,
                                             ushort* __restrict__ d, int i)
{
    const float4 a = reinterpret_cast<const float4*>(s)[2*i + 0];
    const float4 b = reinterpret_cast<const float4*>(s)[2*i + 1];
    ushort u[8];
    u[0] = f2bf(a.x); u[1] = f2bf(a.y); u[2] = f2bf(a.z); u[3] = f2bf(a.w);
    u[4] = f2bf(b.x); u[5] = f2bf(b.y); u[6] = f2bf(b.z); u[7] = f2bf(b.w);
    reinterpret_cast<uint4*>(d)[i] = *reinterpret_cast<uint4*>(u);
}

__global__ __launch_bounds__(256) void prep(PrepArgs a)
{
    int bid = blockIdx.x;
    const int t = threadIdx.x;
    if (bid < 2048) {
        conv8(a.src[0], a.dst[0], bid*256 + t);
        return;
    }
    bid -= 2048;
    if (bid < 2048) {
        const int wi = 1 + (bid >> 9);
        const int i  = (bid & 511)*256 + t;
        conv8(a.src[wi], a.dst[wi], i);
        return;
    }
    bid -= 2048;
    const int i = bid*256 + t;
    if (i < NTOK) a.zero[i] = 0.f;
}

// ---------------------------------------------------------------
// MFMA GEMM (QKV, fused over z): Y = (A @ W^T + bias) * scale.
// z = 0 (Q, pre-scaled by SC2) and z = 1 (K): row-major bf16 out.
// z = 2 (V): writes DIRECTLY TRANSPOSED to Vt[(b*NH+h)][d][s]
// (ushort4 packs of 4 consecutive s), deleting the transpose kernel.
// ---------------------------------------------------------------
struct GemmArgs {
    const ushort* W[3];
    const float*  bias[3];
    void*         Y[3];
    float         scale[3];
    ushort*       Vt;
};

__global__ __launch_bounds__(256) void gemm_qkv(
    const ushort* __restrict__ A, GemmArgs args, int M, int N, int K)
{
    constexpr int MREP = 4;
    constexpr int BM = MREP * 32;
    __shared__ __align__(16) ushort As[BM * 64];
    __shared__ __align__(16) ushort Bs[128 * 64];

    const int z = blockIdx.z;
    const ushort* __restrict__ W   = args.W[z];
    const float*  __restrict__ bia = args.bias[z];
    const float sc = args.scale[z];

    const int t  = threadIdx.x;
    const int w  = t >> 6;
    const int l  = t & 63;
    const int lq = l >> 4;
    const int ln = l & 15;
    const int wr = w >> 1;
    const int wc = w & 1;
    const int m0 = blockIdx.x * BM;
    const int n0 = blockIdx.y * 128;
    const int srow = l >> 3;
    const int scol = (l & 7) * 8;

    f32x4 acc[MREP][4];
#pragma unroll
    for (int m = 0; m < MREP; ++m)
#pragma unroll
        for (int n = 0; n < 4; ++n) acc[m][n] = f32x4{0.f, 0.f, 0.f, 0.f};

    for (int k0 = 0; k0 < K; k0 += 64) {
        __syncthreads();
#pragma unroll
        for (int i = 0; i < BM/32; ++i) {
            const int rb = i*32 + w*8;
            gload_lds16(A + (size_t)(m0 + rb + srow)*K + k0 + scol, &As[rb*64]);
        }
#pragma unroll
        for (int i = 0; i < 4; ++i) {
            const int rb = i*32 + w*8;
            gload_lds16(W + (size_t)(n0 + rb + srow)*K + k0 + scol, &Bs[rb*64]);
        }
        __syncthreads();
#pragma unroll
        for (int ks = 0; ks < 2; ++ks) {
            bf16x8 bfr[4];
#pragma unroll
            for (int n = 0; n < 4; ++n)
                bfr[n] = *reinterpret_cast<const bf16x8*>(&Bs[(wc*64 + n*16 + ln)*64 + ks*32 + lq*8]);
#pragma unroll
            for (int m = 0; m < MREP; ++m) {
                const bf16x8 afr = *reinterpret_cast<const bf16x8*>(&As[(wr*MREP*16 + m*16 + ln)*64 + ks*32 + lq*8]);
#pragma unroll
                for (int n = 0; n < 4; ++n)
                    acc[m][n] = __builtin_amdgcn_mfma_f32_16x16x32_bf16(afr, bfr[n], acc[m][n], 0, 0, 0);
            }
        }
    }

    float bv[4];
#pragma unroll
    for (int n = 0; n < 4; ++n) bv[n] = bia[n0 + wc*64 + n*16 + ln];

    if (z != 2) {
        ushort* Y = (ushort*)args.Y[z];
#pragma unroll
        for (int m = 0; m < MREP; ++m) {
#pragma unroll
            for (int r = 0; r < 4; ++r) {
                const size_t row = (size_t)(m0 + wr*MREP*16 + m*16 + lq*4 + r);
#pragma unroll
                for (int n = 0; n < 4; ++n) {
                    const int col = n0 + wc*64 + n*16 + ln;
                    Y[row*N + col] = f2bf((acc[m][n][r] + bv[n]) * sc);
                }
            }
        }
    } else {
        // V: transposed write. col -> (h = col>>6, d = col&63); row -> (b, s).
        const int b = m0 >> 11;   // 128-row tiles never straddle the b boundary
#pragma unroll
        for (int m = 0; m < MREP; ++m) {
            const int s_base = (m0 & 2047) + wr*MREP*16 + m*16 + lq*4;
#pragma unroll
            for (int n = 0; n < 4; ++n) {
                const int col = n0 + wc*64 + n*16 + ln;
                const int h = col >> 6;
                const int d = col & 63;
                ushort4 u;
                u.x = f2bf(acc[m][n][0] + bv[n]);
                u.y = f2bf(acc[m][n][1] + bv[n]);
                u.z = f2bf(acc[m][n][2] + bv[n]);
                u.w = f2bf(acc[m][n][3] + bv[n]);
                *reinterpret_cast<ushort4*>(
                    args.Vt + ((size_t)((b*NH_ + h)*HD_ + d))*S_ + s_base) = u;
            }
        }
    }
}

// ---------------------------------------------------------------
// attn_pv (round 14 = proven round 12): QB=128, 16x16 swapped QK,
// swizzled Ps with packed b64 stores, pre-scaled Q, ones-MFMA lsum,
// zero-C init, K/V dbuf, one barrier per tile, XCD swizzle.
// ---------------------------------------------------------------
__global__ __launch_bounds__(256, 2) void attn_pv(
    const ushort* __restrict__ Qb, const ushort* __restrict__ Kb,
    const ushort* __restrict__ Vtg, ushort* __restrict__ ctx,
    float* __restrict__ il2_g)
{
    __shared__ __align__(16) ushort Ks0[64*64];
    __shared__ __align__(16) ushort Ks1[64*64];
    __shared__ __align__(16) ushort Vs0[64*64];
    __shared__ __align__(16) ushort Vs1[64*64];
    __shared__ __align__(16) ushort Ps[4][32*64];   // per-wave P, XOR-swizzled

    const int id  = blockIdx.x;
    const int qt_ = (id >> 3) & 15;
    const int bh  = (id & 7) + ((id >> 7) << 3);
    const int b   = bh >> 4;
    const int h   = bh & 15;
    const int q0  = qt_ * 128;

    const int t  = threadIdx.x;
    const int w  = t >> 6;
    const int l  = t & 63;
    const int lq = l >> 4;
    const int ln = l & 15;
    const int ln7 = ln & 7;

    bf16x8 qf[2][2];
#pragma unroll
    for (int qs = 0; qs < 2; ++qs) {
        const ushort* qrow = Qb + ((size_t)(b*S_ + q0 + w*32 + qs*16 + ln))*H_ + h*HD_ + lq*8;
        qf[qs][0] = *reinterpret_cast<const bf16x8*>(qrow);
        qf[qs][1] = *reinterpret_cast<const bf16x8*>(qrow + 32);
    }

    bf16x8 onesb;
#pragma unroll
    for (int j = 0; j < 8; ++j) onesb[j] = (short)0x3F80;

    const f32x4 ZED = f32x4{0.f, 0.f, 0.f, 0.f};

    size_t koff[2], voff[2];
    int    dsto[2];
#pragma unroll
    for (int i = 0; i < 2; ++i) {
        const int chunk = i*256 + t;
        const int row   = chunk >> 3;
        const int c8    = (chunk & 7) ^ (row & 7);
        koff[i] = (size_t)(b*S_ + row)*H_ + h*HD_ + c8*8;
        voff[i] = ((size_t)((b*NH_ + h)*HD_ + row))*S_ + c8*8;
        dsto[i] = chunk*8;
    }

    f32x4 lsacc[2] = {ZED, ZED};
    f32x4 oacc[2][4];
#pragma unroll
    for (int qs = 0; qs < 2; ++qs)
#pragma unroll
        for (int nt = 0; nt < 4; ++nt) oacc[qs][nt] = ZED;

    auto tile_body = [&](const ushort* __restrict__ ksb, const ushort* __restrict__ vsb,
                         int pre_kt, bool do_pre,
                         ushort* __restrict__ kdst, ushort* __restrict__ vdst) {
        if (do_pre) {
#pragma unroll
            for (int i = 0; i < 2; ++i) {
                gload_lds16(Kb + koff[i] + (size_t)pre_kt*H_, &kdst[dsto[i]]);
                gload_lds16(Vtg + voff[i] + pre_kt, &vdst[dsto[i]]);
            }
        }

        // swapped QK^T: sacc[qs][nt], zero-C init at ks=0
        f32x4 sacc[2][4];
        {
            bf16x8 kb[4];
#pragma unroll
            for (int nt = 0; nt < 4; ++nt)
                kb[nt] = *reinterpret_cast<const bf16x8*>(
                    &ksb[(nt*16 + ln)*64 + ((lq ^ ln7) * 8)]);
#pragma unroll
            for (int qs = 0; qs < 2; ++qs)
#pragma unroll
                for (int nt = 0; nt < 4; ++nt)
                    sacc[qs][nt] = __builtin_amdgcn_mfma_f32_16x16x32_bf16(
                        kb[nt], qf[qs][0], ZED, 0, 0, 0);
        }
        {
            bf16x8 kb[4];
#pragma unroll
            for (int nt = 0; nt < 4; ++nt)
                kb[nt] = *reinterpret_cast<const bf16x8*>(
                    &ksb[(nt*16 + ln)*64 + (((4 + lq) ^ ln7) * 8)]);
#pragma unroll
            for (int qs = 0; qs < 2; ++qs)
#pragma unroll
                for (int nt = 0; nt < 4; ++nt)
                    sacc[qs][nt] = __builtin_amdgcn_mfma_f32_16x16x32_bf16(
                        kb[nt], qf[qs][1], sacc[qs][nt], 0, 0, 0);
        }

        // numerators: e = exp2(s); pack; XOR-swizzled Ps store
#pragma unroll
        for (int qs = 0; qs < 2; ++qs) {
#pragma unroll
            for (int nt = 0; nt < 4; ++nt) {
                const float e0 = exp2f(sacc[qs][nt][0]);
                const float e1 = exp2f(sacc[qs][nt][1]);
                const float e2 = exp2f(sacc[qs][nt][2]);
                const float e3 = exp2f(sacc[qs][nt][3]);
                uint2 pk;
                pk.x = cvt_pk_bf16(e0, e1);
                pk.y = cvt_pk_bf16(e2, e3);
                const int wch = (nt*2 + (lq >> 1)) ^ ln7;
                *reinterpret_cast<uint2*>(
                    &Ps[w][(qs*16 + ln)*64 + wch*8 + (lq & 1)*4]) = pk;
            }
        }

        // PV + lsum: vb read once per (ks,nt), used by both qs
#pragma unroll
        for (int ks = 0; ks < 2; ++ks) {
            bf16x8 pa[2];
#pragma unroll
            for (int qs = 0; qs < 2; ++qs) {
                pa[qs] = *reinterpret_cast<const bf16x8*>(
                    &Ps[w][(qs*16 + ln)*64 + (((ks*4 + lq) ^ ln7) * 8)]);
                lsacc[qs] = __builtin_amdgcn_mfma_f32_16x16x32_bf16(
                    pa[qs], onesb, lsacc[qs], 0, 0, 0);
            }
#pragma unroll
            for (int nt = 0; nt < 4; ++nt) {
                const bf16x8 vb8 = *reinterpret_cast<const bf16x8*>(
                    &vsb[(nt*16 + ln)*64 + (((ks*4 + lq) ^ ln7) * 8)]);
#pragma unroll
                for (int qs = 0; qs < 2; ++qs)
                    oacc[qs][nt] = __builtin_amdgcn_mfma_f32_16x16x32_bf16(
                        pa[qs], vb8, oacc[qs][nt], 0, 0, 0);
            }
        }

        __syncthreads();
    };

#pragma unroll
    for (int i = 0; i < 2; ++i) {
        gload_lds16(Kb + koff[i], &Ks0[dsto[i]]);
        gload_lds16(Vtg + voff[i], &Vs0[dsto[i]]);
    }
    __syncthreads();

    for (int kt = 0; kt < S_; kt += 128) {
        tile_body(Ks0, Vs0, kt + 64, true, Ks1, Vs1);
        tile_body(Ks1, Vs1, kt + 128, kt + 128 < S_, Ks0, Vs0);
    }

#pragma unroll
    for (int qs = 0; qs < 2; ++qs) {
        float ivr[4];
#pragma unroll
        for (int r = 0; r < 4; ++r) ivr[r] = 1.f / lsacc[qs][r];

        if (ln == 0) {
            float4 o;
            o.x = -__log2f(lsacc[qs][0]);
            o.y = -__log2f(lsacc[qs][1]);
            o.z = -__log2f(lsacc[qs][2]);
            o.w = -__log2f(lsacc[qs][3]);
            *reinterpret_cast<float4*>(
                il2_g + (size_t)(b*NH_ + h)*S_ + q0 + w*32 + qs*16 + lq*4) = o;
        }

        ushort* crow = ctx + ((size_t)(b*S_ + q0 + w*32 + qs*16 + lq*4))*H_ + h*HD_ + ln;
#pragma unroll
        for (int r = 0; r < 4; ++r)
#pragma unroll
            for (int nt = 0; nt < 4; ++nt)
                crow[(size_t)r*H_ + nt*16] = f2bf(oacc[qs][nt][r] * ivr[r]);
    }
}

// ---------------------------------------------------------------
// fused colsum + out-projection (unchanged from round 12).
// ---------------------------------------------------------------
struct FusedArgs {
    const ushort* Qb; const ushort* Kb;
    const float*  il2; float* avg_out;
    const ushort* A;  const ushort* W;
    const float*  bias; float* Y;
};

__global__ __launch_bounds__(256) void colsum_outproj(FusedArgs fa)
{
    __shared__ __align__(16) char smem[32768];
    const int id = blockIdx.x;
    const int t  = threadIdx.x;
    const int w  = t >> 6;
    const int l  = t & 63;
    const int lq = l >> 4;
    const int ln = l & 15;
    const int ln7 = ln & 7;
    const f32x4 ZED = f32x4{0.f, 0.f, 0.f, 0.f};

    if (id < 1024) {
        ushort* KsT = (ushort*)smem;
        ushort* Qs0 = (ushort*)(smem + 8192);
        ushort* Qs1 = (ushort*)(smem + 16384);
        float*  iv  = (float*)(smem + 24576);

        const int kt_ = (id >> 3) & 31;
        const int bh  = (id & 7) + ((id >> 8) << 3);
        const int b   = bh >> 4;
        const int h   = bh & 15;
        const int k0  = kt_ * 64;

        int crow_[2], cc8[2], dsto[2];
#pragma unroll
        for (int i = 0; i < 2; ++i) {
            const int chunk = i*256 + t;
            crow_[i] = chunk >> 3;
            cc8[i]   = (chunk & 7) ^ (crow_[i] & 7);
            dsto[i]  = chunk*8;
        }

#pragma unroll
        for (int i = 0; i < 2; ++i) {
            gload_lds16(fa.Kb + (size_t)(b*S_ + k0 + crow_[i])*H_ + h*HD_ + cc8[i]*8, &KsT[dsto[i]]);
            gload_lds16(fa.il2 + (size_t)bh*S_ + (i*256 + t)*4, &iv[(i*256 + t)*4]);
            gload_lds16(fa.Qb + (size_t)(b*S_ + crow_[i])*H_ + h*HD_ + cc8[i]*8, &Qs0[dsto[i]]);
        }
        __syncthreads();

        bf16x8 kf[2];
#pragma unroll
        for (int ks = 0; ks < 2; ++ks)
            kf[ks] = *reinterpret_cast<const bf16x8*>(
                &KsT[(w*16 + ln)*64 + (((ks*4 + lq) ^ ln7) * 8)]);

        float cs4[4] = {0.f, 0.f, 0.f, 0.f};

        for (int qt = 0; qt < S_; qt += 128) {
#pragma unroll
            for (int i = 0; i < 2; ++i)
                gload_lds16(fa.Qb + (size_t)(b*S_ + qt + 64 + crow_[i])*H_ + h*HD_ + cc8[i]*8,
                            &Qs1[dsto[i]]);
#pragma unroll
            for (int c = 0; c < 4; ++c) {
                const bf16x8 a0 = *reinterpret_cast<const bf16x8*>(
                    &Qs0[(c*16 + ln)*64 + ((lq ^ ln7) * 8)]);
                const bf16x8 a1 = *reinterpret_cast<const bf16x8*>(
                    &Qs0[(c*16 + ln)*64 + (((4 + lq) ^ ln7) * 8)]);
                f32x4 sacc = __builtin_amdgcn_mfma_f32_16x16x32_bf16(a0, kf[0], ZED, 0, 0, 0);
                sacc = __builtin_amdgcn_mfma_f32_16x16x32_bf16(a1, kf[1], sacc, 0, 0, 0);
                const f32x4 iv4 = *reinterpret_cast<const f32x4*>(&iv[qt + c*16 + lq*4]);
#pragma unroll
                for (int r = 0; r < 4; ++r)
                    cs4[r] += exp2f(sacc[r] + iv4[r]);
            }
            __syncthreads();

            if (qt + 128 < S_) {
#pragma unroll
                for (int i = 0; i < 2; ++i)
                    gload_lds16(fa.Qb + (size_t)(b*S_ + qt + 128 + crow_[i])*H_ + h*HD_ + cc8[i]*8,
                                &Qs0[dsto[i]]);
            }
#pragma unroll
            for (int c = 0; c < 4; ++c) {
                const bf16x8 a0 = *reinterpret_cast<const bf16x8*>(
                    &Qs1[(c*16 + ln)*64 + ((lq ^ ln7) * 8)]);
                const bf16x8 a1 = *reinterpret_cast<const bf16x8*>(
                    &Qs1[(c*16 + ln)*64 + (((4 + lq) ^ ln7) * 8)]);
                f32x4 sacc = __builtin_amdgcn_mfma_f32_16x16x32_bf16(a0, kf[0], ZED, 0, 0, 0);
                sacc = __builtin_amdgcn_mfma_f32_16x16x32_bf16(a1, kf[1], sacc, 0, 0, 0);
                const f32x4 iv4 = *reinterpret_cast<const f32x4*>(&iv[qt + 64 + c*16 + lq*4]);
#pragma unroll
                for (int r = 0; r < 4; ++r)
                    cs4[r] += exp2f(sacc[r] + iv4[r]);
            }
            __syncthreads();
        }

        float cs = (cs4[0] + cs4[1]) + (cs4[2] + cs4[3]);
        cs += __shfl_xor(cs, 16);
        cs += __shfl_xor(cs, 32);
        if (l < 16)
            atomicAdd(&fa.avg_out[(size_t)b*S_ + k0 + w*16 + l], cs * AVGINV);
    } else {
        ushort* As = (ushort*)smem;
        ushort* Bs = (ushort*)(smem + 8192);

        const int g  = id - 1024;
        const int m0 = (g & 63) * 64;
        const int n0 = (g >> 6) * 128;
        const int wr = w >> 1;
        const int wc = w & 1;
        const int srow = l >> 3;
        const int scol = (l & 7) * 8;

        f32x4 acc[2][4];
#pragma unroll
        for (int m = 0; m < 2; ++m)
#pragma unroll
            for (int n = 0; n < 4; ++n) acc[m][n] = ZED;

        for (int k0 = 0; k0 < H_; k0 += 64) {
            __syncthreads();
#pragma unroll
            for (int i = 0; i < 2; ++i) {
                const int rb = i*32 + w*8;
                gload_lds16(fa.A + (size_t)(m0 + rb + srow)*H_ + k0 + scol, &As[rb*64]);
            }
#pragma unroll
            for (int i = 0; i < 4; ++i) {
                const int rb = i*32 + w*8;
                gload_lds16(fa.W + (size_t)(n0 + rb + srow)*H_ + k0 + scol, &Bs[rb*64]);
            }
            __syncthreads();
#pragma unroll
            for (int ks = 0; ks < 2; ++ks) {
                bf16x8 bfr[4];
#pragma unroll
                for (int n = 0; n < 4; ++n)
                    bfr[n] = *reinterpret_cast<const bf16x8*>(&Bs[(wc*64 + n*16 + ln)*64 + ks*32 + lq*8]);
#pragma unroll
                for (int m = 0; m < 2; ++m) {
                    const bf16x8 afr = *reinterpret_cast<const bf16x8*>(&As[(wr*32 + m*16 + ln)*64 + ks*32 + lq*8]);
#pragma unroll
                    for (int n = 0; n < 4; ++n)
                        acc[m][n] = __builtin_amdgcn_mfma_f32_16x16x32_bf16(afr, bfr[n], acc[m][n], 0, 0, 0);
                }
            }
        }

        float bv[4];
#pragma unroll
        for (int n = 0; n < 4; ++n) bv[n] = fa.bias[n0 + wc*64 + n*16 + ln];

#pragma unroll
        for (int m = 0; m < 2; ++m) {
#pragma unroll
            for (int r = 0; r < 4; ++r) {
                const size_t row = (size_t)(m0 + wr*32 + m*16 + lq*4 + r);
#pragma unroll
                for (int n = 0; n < 4; ++n) {
                    const int col = n0 + wc*64 + n*16 + ln;
                    fa.Y[row*H_ + col] = acc[m][n][r] + bv[n];
                }
            }
        }
    }
}

extern "C" void kernel_launch(void* const* d_in, const int* in_sizes, int n_in,
                              void* d_out, int out_size, void* d_ws, size_t ws_size,
                              hipStream_t stream)
{
    const float* x  = (const float*)d_in[0];
    const float* Wq = (const float*)d_in[1];
    const float* bq = (const float*)d_in[2];
    const float* Wk = (const float*)d_in[3];
    const float* bk = (const float*)d_in[4];
    const float* Wv = (const float*)d_in[5];
    const float* bv = (const float*)d_in[6];
    const float* Wo = (const float*)d_in[7];
    const float* bo = (const float*)d_in[8];

    float* out     = (float*)d_out;
    float* avg_out = out + (size_t)NTOK * H_;

    char* ws = (char*)d_ws;
    const size_t mat  = (size_t)NTOK * H_ * sizeof(ushort);   // 8 MB
    const size_t wmat = (size_t)H_ * H_ * sizeof(ushort);     // 2 MB
    ushort* xb   = (ushort*)(ws);                  // also ctx (x dead after projections)
    ushort* Qb   = (ushort*)(ws + mat);
    ushort* Kb   = (ushort*)(ws + 2*mat);
    ushort* Vtg  = (ushort*)(ws + 3*mat);          // V^T [(b,h)][d][s], written by gemm_qkv
    ushort* Wqb  = (ushort*)(ws + 4*mat);
    ushort* Wkb  = (ushort*)(ws + 4*mat + wmat);
    ushort* Wvb  = (ushort*)(ws + 4*mat + 2*wmat);
    ushort* Wob  = (ushort*)(ws + 4*mat + 3*wmat);
    float*  il2  = (float*)(ws + 4*mat + 4*wmat);              // 256 KB
    ushort* ctxb = xb;

    const dim3 blk(256);

    // 1) all converts + avg_out zero, one launch
    {
        PrepArgs pa;
        pa.src[0] = x;  pa.dst[0] = xb;
        pa.src[1] = Wq; pa.dst[1] = Wqb;
        pa.src[2] = Wk; pa.dst[2] = Wkb;
        pa.src[3] = Wv; pa.dst[3] = Wvb;
        pa.src[4] = Wo; pa.dst[4] = Wob;
        pa.zero = avg_out;
        prep<<<dim3(4112), blk, 0, stream>>>(pa);
    }

    // 2) fused QKV projections (Q pre-scaled; V written transposed)
    {
        GemmArgs ga;
        ga.W[0] = Wqb; ga.W[1] = Wkb; ga.W[2] = Wvb;
        ga.bias[0] = bq; ga.bias[1] = bk; ga.bias[2] = bv;
        ga.Y[0] = Qb; ga.Y[1] = Kb; ga.Y[2] = nullptr;
        ga.scale[0] = SC2; ga.scale[1] = 1.f; ga.scale[2] = 1.f;
        ga.Vt = Vtg;
        gemm_qkv<<<dim3(NTOK/128, H_/128, 3), blk, 0, stream>>>(xb, ga, NTOK, H_, H_);
    }

    // 3) PV sweep, QB=128, XCD-swizzled 512-block grid
    attn_pv<<<dim3(512), blk, 0, stream>>>(Qb, Kb, Vtg, ctxb, il2);

    // 4) colsum (direct avg accumulate) || out-projection
    {
        FusedArgs fa;
        fa.Qb = Qb; fa.Kb = Kb; fa.il2 = il2; fa.avg_out = avg_out;
        fa.A = ctxb; fa.W = Wob; fa.bias = bo; fa.Y = out;
        colsum_outproj<<<dim3(1536), blk, 0, stream>>>(fa);
    }
}

// Round 15
// 166.353 us; speedup vs baseline: 1.0501x; 1.0045x over previous
//
#include <hip/hip_runtime.h>
#include <hip/hip_bf16.h>

#define B_  2
#define S_  2048
#define H_  1024
#define NH_ 16
#define HD_ 64
#define NTOK (B_*S_)   // 4096

typedef __attribute__((ext_vector_type(8))) short bf16x8;
typedef __attribute__((ext_vector_type(4))) float f32x4;

#define SC2 0.18033688011112042f   // (1/sqrt(64)) * log2(e)
#define AVGINV (1.f/((float)NH_*(float)S_))

static __device__ __forceinline__ ushort f2bf(float f) {
    __hip_bfloat16 h = __float2bfloat16(f);
    return *reinterpret_cast<ushort*>(&h);
}
static __device__ __forceinline__ uint cvt_pk_bf16(float lo, float hi) {
    uint r;
    asm("v_cvt_pk_bf16_f32 %0, %1, %2" : "=v"(r) : "v"(lo), "v"(hi));
    return r;
}

static __device__ __forceinline__ void gload_lds16(const void* g, void* l) {
    __builtin_amdgcn_global_load_lds(
        (const __attribute__((address_space(1))) void*)g,
        (__attribute__((address_space(3))) void*)l,
        16, 0, 0);
}

// ---------------------------------------------------------------
// prep: all f32->bf16 converts + avg_out zero in ONE launch.
// ---------------------------------------------------------------
struct PrepArgs {
    const float* src[5];   // x, Wq, Wk, Wv, Wo
    ushort*      dst[5];
    float*       zero;     // avg_out
};

static __device__ __forceinline__ void conv8(const float* __restrict__ s,
                                             ushort* __restrict__ d, int i)
{
    const float4 a = reinterpret_cast<const float4*>(s)[2*i + 0];
    const float4 b = reinterpret_cast<const float4*>(s)[2*i + 1];
    ushort u[8];
    u[0] = f2bf(a.x); u[1] = f2bf(a.y); u[2] = f2bf(a.z); u[3] = f2bf(a.w);
    u[4] = f2bf(b.x); u[5] = f2bf(b.y); u[6] = f2bf(b.z); u[7] = f2bf(b.w);
    reinterpret_cast<uint4*>(d)[i] = *reinterpret_cast<uint4*>(u);
}

__global__ __launch_bounds__(256) void prep(PrepArgs a)
{
    int bid = blockIdx.x;
    const int t = threadIdx.x;
    if (bid < 2048) {
        conv8(a.src[0], a.dst[0], bid*256 + t);
        return;
    }
    bid -= 2048;
    if (bid < 2048) {
        const int wi = 1 + (bid >> 9);
        const int i  = (bid & 511)*256 + t;
        conv8(a.src[wi], a.dst[wi], i);
        return;
    }
    bid -= 2048;
    const int i = bid*256 + t;
    if (i < NTOK) a.zero[i] = 0.f;
}

// ---------------------------------------------------------------
// MFMA GEMM (QKV, fused over z): Y = (A @ W^T + bias) * scale.
// z = 0 (Q, pre-scaled by SC2) and z = 1 (K): row-major bf16 out.
// z = 2 (V): writes DIRECTLY TRANSPOSED to Vt[(b*NH+h)][d][s].
// ---------------------------------------------------------------
struct GemmArgs {
    const ushort* W[3];
    const float*  bias[3];
    void*         Y[3];
    float         scale[3];
    ushort*       Vt;
};

__global__ __launch_bounds__(256) void gemm_qkv(
    const ushort* __restrict__ A, GemmArgs args, int M, int N, int K)
{
    constexpr int MREP = 4;
    constexpr int BM = MREP * 32;
    __shared__ __align__(16) ushort As[BM * 64];
    __shared__ __align__(16) ushort Bs[128 * 64];

    const int z = blockIdx.z;
    const ushort* __restrict__ W   = args.W[z];
    const float*  __restrict__ bia = args.bias[z];
    const float sc = args.scale[z];

    const int t  = threadIdx.x;
    const int w  = t >> 6;
    const int l  = t & 63;
    const int lq = l >> 4;
    const int ln = l & 15;
    const int wr = w >> 1;
    const int wc = w & 1;
    const int m0 = blockIdx.x * BM;
    const int n0 = blockIdx.y * 128;
    const int srow = l >> 3;
    const int scol = (l & 7) * 8;

    f32x4 acc[MREP][4];
#pragma unroll
    for (int m = 0; m < MREP; ++m)
#pragma unroll
        for (int n = 0; n < 4; ++n) acc[m][n] = f32x4{0.f, 0.f, 0.f, 0.f};

    for (int k0 = 0; k0 < K; k0 += 64) {
        __syncthreads();
#pragma unroll
        for (int i = 0; i < BM/32; ++i) {
            const int rb = i*32 + w*8;
            gload_lds16(A + (size_t)(m0 + rb + srow)*K + k0 + scol, &As[rb*64]);
        }
#pragma unroll
        for (int i = 0; i < 4; ++i) {
            const int rb = i*32 + w*8;
            gload_lds16(W + (size_t)(n0 + rb + srow)*K + k0 + scol, &Bs[rb*64]);
        }
        __syncthreads();
#pragma unroll
        for (int ks = 0; ks < 2; ++ks) {
            bf16x8 bfr[4];
#pragma unroll
            for (int n = 0; n < 4; ++n)
                bfr[n] = *reinterpret_cast<const bf16x8*>(&Bs[(wc*64 + n*16 + ln)*64 + ks*32 + lq*8]);
#pragma unroll
            for (int m = 0; m < MREP; ++m) {
                const bf16x8 afr = *reinterpret_cast<const bf16x8*>(&As[(wr*MREP*16 + m*16 + ln)*64 + ks*32 + lq*8]);
#pragma unroll
                for (int n = 0; n < 4; ++n)
                    acc[m][n] = __builtin_amdgcn_mfma_f32_16x16x32_bf16(afr, bfr[n], acc[m][n], 0, 0, 0);
            }
        }
    }

    float bv[4];
#pragma unroll
    for (int n = 0; n < 4; ++n) bv[n] = bia[n0 + wc*64 + n*16 + ln];

    if (z != 2) {
        ushort* Y = (ushort*)args.Y[z];
#pragma unroll
        for (int m = 0; m < MREP; ++m) {
#pragma unroll
            for (int r = 0; r < 4; ++r) {
                const size_t row = (size_t)(m0 + wr*MREP*16 + m*16 + lq*4 + r);
#pragma unroll
                for (int n = 0; n < 4; ++n) {
                    const int col = n0 + wc*64 + n*16 + ln;
                    Y[row*N + col] = f2bf((acc[m][n][r] + bv[n]) * sc);
                }
            }
        }
    } else {
        // V: transposed write. col -> (h = col>>6, d = col&63); row -> (b, s).
        const int b = m0 >> 11;
#pragma unroll
        for (int m = 0; m < MREP; ++m) {
            const int s_base = (m0 & 2047) + wr*MREP*16 + m*16 + lq*4;
#pragma unroll
            for (int n = 0; n < 4; ++n) {
                const int col = n0 + wc*64 + n*16 + ln;
                const int h = col >> 6;
                const int d = col & 63;
                ushort4 u;
                u.x = f2bf(acc[m][n][0] + bv[n]);
                u.y = f2bf(acc[m][n][1] + bv[n]);
                u.z = f2bf(acc[m][n][2] + bv[n]);
                u.w = f2bf(acc[m][n][3] + bv[n]);
                *reinterpret_cast<ushort4*>(
                    args.Vt + ((size_t)((b*NH_ + h)*HD_ + d))*S_ + s_base) = u;
            }
        }
    }
}

// ---------------------------------------------------------------
// attn_pv (unchanged, proven round 12/14)
// ---------------------------------------------------------------
__global__ __launch_bounds__(256, 2) void attn_pv(
    const ushort* __restrict__ Qb, const ushort* __restrict__ Kb,
    const ushort* __restrict__ Vtg, ushort* __restrict__ ctx,
    float* __restrict__ il2_g)
{
    __shared__ __align__(16) ushort Ks0[64*64];
    __shared__ __align__(16) ushort Ks1[64*64];
    __shared__ __align__(16) ushort Vs0[64*64];
    __shared__ __align__(16) ushort Vs1[64*64];
    __shared__ __align__(16) ushort Ps[4][32*64];

    const int id  = blockIdx.x;
    const int qt_ = (id >> 3) & 15;
    const int bh  = (id & 7) + ((id >> 7) << 3);
    const int b   = bh >> 4;
    const int h   = bh & 15;
    const int q0  = qt_ * 128;

    const int t  = threadIdx.x;
    const int w  = t >> 6;
    const int l  = t & 63;
    const int lq = l >> 4;
    const int ln = l & 15;
    const int ln7 = ln & 7;

    bf16x8 qf[2][2];
#pragma unroll
    for (int qs = 0; qs < 2; ++qs) {
        const ushort* qrow = Qb + ((size_t)(b*S_ + q0 + w*32 + qs*16 + ln))*H_ + h*HD_ + lq*8;
        qf[qs][0] = *reinterpret_cast<const bf16x8*>(qrow);
        qf[qs][1] = *reinterpret_cast<const bf16x8*>(qrow + 32);
    }

    bf16x8 onesb;
#pragma unroll
    for (int j = 0; j < 8; ++j) onesb[j] = (short)0x3F80;

    const f32x4 ZED = f32x4{0.f, 0.f, 0.f, 0.f};

    size_t koff[2], voff[2];
    int    dsto[2];
#pragma unroll
    for (int i = 0; i < 2; ++i) {
        const int chunk = i*256 + t;
        const int row   = chunk >> 3;
        const int c8    = (chunk & 7) ^ (row & 7);
        koff[i] = (size_t)(b*S_ + row)*H_ + h*HD_ + c8*8;
        voff[i] = ((size_t)((b*NH_ + h)*HD_ + row))*S_ + c8*8;
        dsto[i] = chunk*8;
    }

    f32x4 lsacc[2] = {ZED, ZED};
    f32x4 oacc[2][4];
#pragma unroll
    for (int qs = 0; qs < 2; ++qs)
#pragma unroll
        for (int nt = 0; nt < 4; ++nt) oacc[qs][nt] = ZED;

    auto tile_body = [&](const ushort* __restrict__ ksb, const ushort* __restrict__ vsb,
                         int pre_kt, bool do_pre,
                         ushort* __restrict__ kdst, ushort* __restrict__ vdst) {
        if (do_pre) {
#pragma unroll
            for (int i = 0; i < 2; ++i) {
                gload_lds16(Kb + koff[i] + (size_t)pre_kt*H_, &kdst[dsto[i]]);
                gload_lds16(Vtg + voff[i] + pre_kt, &vdst[dsto[i]]);
            }
        }

        f32x4 sacc[2][4];
        {
            bf16x8 kb[4];
#pragma unroll
            for (int nt = 0; nt < 4; ++nt)
                kb[nt] = *reinterpret_cast<const bf16x8*>(
                    &ksb[(nt*16 + ln)*64 + ((lq ^ ln7) * 8)]);
#pragma unroll
            for (int qs = 0; qs < 2; ++qs)
#pragma unroll
                for (int nt = 0; nt < 4; ++nt)
                    sacc[qs][nt] = __builtin_amdgcn_mfma_f32_16x16x32_bf16(
                        kb[nt], qf[qs][0], ZED, 0, 0, 0);
        }
        {
            bf16x8 kb[4];
#pragma unroll
            for (int nt = 0; nt < 4; ++nt)
                kb[nt] = *reinterpret_cast<const bf16x8*>(
                    &ksb[(nt*16 + ln)*64 + (((4 + lq) ^ ln7) * 8)]);
#pragma unroll
            for (int qs = 0; qs < 2; ++qs)
#pragma unroll
                for (int nt = 0; nt < 4; ++nt)
                    sacc[qs][nt] = __builtin_amdgcn_mfma_f32_16x16x32_bf16(
                        kb[nt], qf[qs][1], sacc[qs][nt], 0, 0, 0);
        }

#pragma unroll
        for (int qs = 0; qs < 2; ++qs) {
#pragma unroll
            for (int nt = 0; nt < 4; ++nt) {
                const float e0 = exp2f(sacc[qs][nt][0]);
                const float e1 = exp2f(sacc[qs][nt][1]);
                const float e2 = exp2f(sacc[qs][nt][2]);
                const float e3 = exp2f(sacc[qs][nt][3]);
                uint2 pk;
                pk.x = cvt_pk_bf16(e0, e1);
                pk.y = cvt_pk_bf16(e2, e3);
                const int wch = (nt*2 + (lq >> 1)) ^ ln7;
                *reinterpret_cast<uint2*>(
                    &Ps[w][(qs*16 + ln)*64 + wch*8 + (lq & 1)*4]) = pk;
            }
        }

#pragma unroll
        for (int ks = 0; ks < 2; ++ks) {
            bf16x8 pa[2];
#pragma unroll
            for (int qs = 0; qs < 2; ++qs) {
                pa[qs] = *reinterpret_cast<const bf16x8*>(
                    &Ps[w][(qs*16 + ln)*64 + (((ks*4 + lq) ^ ln7) * 8)]);
                lsacc[qs] = __builtin_amdgcn_mfma_f32_16x16x32_bf16(
                    pa[qs], onesb, lsacc[qs], 0, 0, 0);
            }
#pragma unroll
            for (int nt = 0; nt < 4; ++nt) {
                const bf16x8 vb8 = *reinterpret_cast<const bf16x8*>(
                    &vsb[(nt*16 + ln)*64 + (((ks*4 + lq) ^ ln7) * 8)]);
#pragma unroll
                for (int qs = 0; qs < 2; ++qs)
                    oacc[qs][nt] = __builtin_amdgcn_mfma_f32_16x16x32_bf16(
                        pa[qs], vb8, oacc[qs][nt], 0, 0, 0);
            }
        }

        __syncthreads();
    };

#pragma unroll
    for (int i = 0; i < 2; ++i) {
        gload_lds16(Kb + koff[i], &Ks0[dsto[i]]);
        gload_lds16(Vtg + voff[i], &Vs0[dsto[i]]);
    }
    __syncthreads();

    for (int kt = 0; kt < S_; kt += 128) {
        tile_body(Ks0, Vs0, kt + 64, true, Ks1, Vs1);
        tile_body(Ks1, Vs1, kt + 128, kt + 128 < S_, Ks0, Vs0);
    }

#pragma unroll
    for (int qs = 0; qs < 2; ++qs) {
        float ivr[4];
#pragma unroll
        for (int r = 0; r < 4; ++r) ivr[r] = 1.f / lsacc[qs][r];

        if (ln == 0) {
            float4 o;
            o.x = -__log2f(lsacc[qs][0]);
            o.y = -__log2f(lsacc[qs][1]);
            o.z = -__log2f(lsacc[qs][2]);
            o.w = -__log2f(lsacc[qs][3]);
            *reinterpret_cast<float4*>(
                il2_g + (size_t)(b*NH_ + h)*S_ + q0 + w*32 + qs*16 + lq*4) = o;
        }

        ushort* crow = ctx + ((size_t)(b*S_ + q0 + w*32 + qs*16 + lq*4))*H_ + h*HD_ + ln;
#pragma unroll
        for (int r = 0; r < 4; ++r)
#pragma unroll
            for (int nt = 0; nt < 4; ++nt)
                crow[(size_t)r*H_ + nt*16] = f2bf(oacc[qs][nt][r] * ivr[r]);
    }
}

// ---------------------------------------------------------------
// fused colsum + out-projection (round 15).
// blocks [0,512): colsum with 128-KEY tiles (kf[2][2] reg hoist) —
// halves Q/iv LDS traffic per key (LDS was the bound). XCD swizzle.
// blocks [512,1024): out-proj GEMM BM=64 (unchanged).
// LDS union 40 KB -> 4 blocks/CU.
// ---------------------------------------------------------------
struct FusedArgs {
    const ushort* Qb; const ushort* Kb;
    const float*  il2; float* avg_out;
    const ushort* A;  const ushort* W;
    const float*  bias; float* Y;
};

__global__ __launch_bounds__(256) void colsum_outproj(FusedArgs fa)
{
    __shared__ __align__(16) char smem[40960];
    const int id = blockIdx.x;
    const int t  = threadIdx.x;
    const int w  = t >> 6;
    const int l  = t & 63;
    const int lq = l >> 4;
    const int ln = l & 15;
    const int ln7 = ln & 7;
    const f32x4 ZED = f32x4{0.f, 0.f, 0.f, 0.f};

    if (id < 512) {
        // -------- colsum role: 128 keys/block, XCD-swizzled --------
        ushort* KsT = (ushort*)smem;              // 16 KB (128 rows)
        ushort* Qs0 = (ushort*)(smem + 16384);    // 8 KB
        ushort* Qs1 = (ushort*)(smem + 24576);    // 8 KB
        float*  iv  = (float*)(smem + 32768);     // 8 KB

        const int kt_ = (id >> 3) & 15;
        const int bh  = (id & 7) + ((id >> 7) << 3);
        const int b   = bh >> 4;
        const int h   = bh & 15;
        const int k0  = kt_ * 128;

        int crow_[2], cc8[2], dsto[2];
#pragma unroll
        for (int i = 0; i < 2; ++i) {
            const int chunk = i*256 + t;
            crow_[i] = chunk >> 3;
            cc8[i]   = (chunk & 7) ^ (crow_[i] & 7);
            dsto[i]  = chunk*8;
        }

        // stage K (1024 chunks = 4/thread), iv (2/thread), Q(0) (2/thread)
#pragma unroll
        for (int i = 0; i < 4; ++i) {
            const int chunk = i*256 + t;
            const int row   = chunk >> 3;
            const int c8    = (chunk & 7) ^ (row & 7);
            gload_lds16(fa.Kb + (size_t)(b*S_ + k0 + row)*H_ + h*HD_ + c8*8, &KsT[chunk*8]);
        }
#pragma unroll
        for (int i = 0; i < 2; ++i) {
            gload_lds16(fa.il2 + (size_t)bh*S_ + (i*256 + t)*4, &iv[(i*256 + t)*4]);
            gload_lds16(fa.Qb + (size_t)(b*S_ + crow_[i])*H_ + h*HD_ + cc8[i]*8, &Qs0[dsto[i]]);
        }
        __syncthreads();

        // hoist this wave's K B-fragments: keys w*32 + sub*16 + ln
        bf16x8 kf[2][2];
#pragma unroll
        for (int sub = 0; sub < 2; ++sub)
#pragma unroll
            for (int ks = 0; ks < 2; ++ks)
                kf[sub][ks] = *reinterpret_cast<const bf16x8*>(
                    &KsT[(w*32 + sub*16 + ln)*64 + (((ks*4 + lq) ^ ln7) * 8)]);

        float cs4[2][4] = {{0.f,0.f,0.f,0.f},{0.f,0.f,0.f,0.f}};

        for (int qt = 0; qt < S_; qt += 128) {
            // phase A: compute Qs0, prefetch qt+64 -> Qs1
#pragma unroll
            for (int i = 0; i < 2; ++i)
                gload_lds16(fa.Qb + (size_t)(b*S_ + qt + 64 + crow_[i])*H_ + h*HD_ + cc8[i]*8,
                            &Qs1[dsto[i]]);
#pragma unroll
            for (int c = 0; c < 4; ++c) {
                const bf16x8 a0 = *reinterpret_cast<const bf16x8*>(
                    &Qs0[(c*16 + ln)*64 + ((lq ^ ln7) * 8)]);
                const bf16x8 a1 = *reinterpret_cast<const bf16x8*>(
                    &Qs0[(c*16 + ln)*64 + (((4 + lq) ^ ln7) * 8)]);
                const f32x4 iv4 = *reinterpret_cast<const f32x4*>(&iv[qt + c*16 + lq*4]);
#pragma unroll
                for (int sub = 0; sub < 2; ++sub) {
                    f32x4 sacc = __builtin_amdgcn_mfma_f32_16x16x32_bf16(a0, kf[sub][0], ZED, 0, 0, 0);
                    sacc = __builtin_amdgcn_mfma_f32_16x16x32_bf16(a1, kf[sub][1], sacc, 0, 0, 0);
#pragma unroll
                    for (int r = 0; r < 4; ++r)
                        cs4[sub][r] += exp2f(sacc[r] + iv4[r]);
                }
            }
            __syncthreads();

            // phase B: compute Qs1, prefetch qt+128 -> Qs0
            if (qt + 128 < S_) {
#pragma unroll
                for (int i = 0; i < 2; ++i)
                    gload_lds16(fa.Qb + (size_t)(b*S_ + qt + 128 + crow_[i])*H_ + h*HD_ + cc8[i]*8,
                                &Qs0[dsto[i]]);
            }
#pragma unroll
            for (int c = 0; c < 4; ++c) {
                const bf16x8 a0 = *reinterpret_cast<const bf16x8*>(
                    &Qs1[(c*16 + ln)*64 + ((lq ^ ln7) * 8)]);
                const bf16x8 a1 = *reinterpret_cast<const bf16x8*>(
                    &Qs1[(c*16 + ln)*64 + (((4 + lq) ^ ln7) * 8)]);
                const f32x4 iv4 = *reinterpret_cast<const f32x4*>(&iv[qt + 64 + c*16 + lq*4]);
#pragma unroll
                for (int sub = 0; sub < 2; ++sub) {
                    f32x4 sacc = __builtin_amdgcn_mfma_f32_16x16x32_bf16(a0, kf[sub][0], ZED, 0, 0, 0);
                    sacc = __builtin_amdgcn_mfma_f32_16x16x32_bf16(a1, kf[sub][1], sacc, 0, 0, 0);
#pragma unroll
                    for (int r = 0; r < 4; ++r)
                        cs4[sub][r] += exp2f(sacc[r] + iv4[r]);
                }
            }
            __syncthreads();
        }

#pragma unroll
        for (int sub = 0; sub < 2; ++sub) {
            float cs = (cs4[sub][0] + cs4[sub][1]) + (cs4[sub][2] + cs4[sub][3]);
            cs += __shfl_xor(cs, 16);
            cs += __shfl_xor(cs, 32);
            if (l < 16)
                atomicAdd(&fa.avg_out[(size_t)b*S_ + k0 + w*32 + sub*16 + l], cs * AVGINV);
        }
    } else {
        // -------- out-projection role (BM=64, BN=128, f32 out) --------
        ushort* As = (ushort*)smem;               // 8 KB
        ushort* Bs = (ushort*)(smem + 8192);      // 16 KB

        const int g  = id - 512;
        const int m0 = (g & 63) * 64;
        const int n0 = (g >> 6) * 128;
        const int wr = w >> 1;
        const int wc = w & 1;
        const int srow = l >> 3;
        const int scol = (l & 7) * 8;

        f32x4 acc[2][4];
#pragma unroll
        for (int m = 0; m < 2; ++m)
#pragma unroll
            for (int n = 0; n < 4; ++n) acc[m][n] = ZED;

        for (int k0 = 0; k0 < H_; k0 += 64) {
            __syncthreads();
#pragma unroll
            for (int i = 0; i < 2; ++i) {
                const int rb = i*32 + w*8;
                gload_lds16(fa.A + (size_t)(m0 + rb + srow)*H_ + k0 + scol, &As[rb*64]);
            }
#pragma unroll
            for (int i = 0; i < 4; ++i) {
                const int rb = i*32 + w*8;
                gload_lds16(fa.W + (size_t)(n0 + rb + srow)*H_ + k0 + scol, &Bs[rb*64]);
            }
            __syncthreads();
#pragma unroll
            for (int ks = 0; ks < 2; ++ks) {
                bf16x8 bfr[4];
#pragma unroll
                for (int n = 0; n < 4; ++n)
                    bfr[n] = *reinterpret_cast<const bf16x8*>(&Bs[(wc*64 + n*16 + ln)*64 + ks*32 + lq*8]);
#pragma unroll
                for (int m = 0; m < 2; ++m) {
                    const bf16x8 afr = *reinterpret_cast<const bf16x8*>(&As[(wr*32 + m*16 + ln)*64 + ks*32 + lq*8]);
#pragma unroll
                    for (int n = 0; n < 4; ++n)
                        acc[m][n] = __builtin_amdgcn_mfma_f32_16x16x32_bf16(afr, bfr[n], acc[m][n], 0, 0, 0);
                }
            }
        }

        float bv[4];
#pragma unroll
        for (int n = 0; n < 4; ++n) bv[n] = fa.bias[n0 + wc*64 + n*16 + ln];

#pragma unroll
        for (int m = 0; m < 2; ++m) {
#pragma unroll
            for (int r = 0; r < 4; ++r) {
                const size_t row = (size_t)(m0 + wr*32 + m*16 + lq*4 + r);
#pragma unroll
                for (int n = 0; n < 4; ++n) {
                    const int col = n0 + wc*64 + n*16 + ln;
                    fa.Y[row*H_ + col] = acc[m][n][r] + bv[n];
                }
            }
        }
    }
}

extern "C" void kernel_launch(void* const* d_in, const int* in_sizes, int n_in,
                              void* d_out, int out_size, void* d_ws, size_t ws_size,
                              hipStream_t stream)
{
    const float* x  = (const float*)d_in[0];
    const float* Wq = (const float*)d_in[1];
    const float* bq = (const float*)d_in[2];
    const float* Wk = (const float*)d_in[3];
    const float* bk = (const float*)d_in[4];
    const float* Wv = (const float*)d_in[5];
    const float* bv = (const float*)d_in[6];
    const float* Wo = (const float*)d_in[7];
    const float* bo = (const float*)d_in[8];

    float* out     = (float*)d_out;
    float* avg_out = out + (size_t)NTOK * H_;

    char* ws = (char*)d_ws;
    const size_t mat  = (size_t)NTOK * H_ * sizeof(ushort);   // 8 MB
    const size_t wmat = (size_t)H_ * H_ * sizeof(ushort);     // 2 MB
    ushort* xb   = (ushort*)(ws);                  // also ctx
    ushort* Qb   = (ushort*)(ws + mat);
    ushort* Kb   = (ushort*)(ws + 2*mat);
    ushort* Vtg  = (ushort*)(ws + 3*mat);          // V^T, written by gemm_qkv
    ushort* Wqb  = (ushort*)(ws + 4*mat);
    ushort* Wkb  = (ushort*)(ws + 4*mat + wmat);
    ushort* Wvb  = (ushort*)(ws + 4*mat + 2*wmat);
    ushort* Wob  = (ushort*)(ws + 4*mat + 3*wmat);
    float*  il2  = (float*)(ws + 4*mat + 4*wmat);  // 256 KB
    ushort* ctxb = xb;

    const dim3 blk(256);

    {
        PrepArgs pa;
        pa.src[0] = x;  pa.dst[0] = xb;
        pa.src[1] = Wq; pa.dst[1] = Wqb;
        pa.src[2] = Wk; pa.dst[2] = Wkb;
        pa.src[3] = Wv; pa.dst[3] = Wvb;
        pa.src[4] = Wo; pa.dst[4] = Wob;
        pa.zero = avg_out;
        prep<<<dim3(4112), blk, 0, stream>>>(pa);
    }

    {
        GemmArgs ga;
        ga.W[0] = Wqb; ga.W[1] = Wkb; ga.W[2] = Wvb;
        ga.bias[0] = bq; ga.bias[1] = bk; ga.bias[2] = bv;
        ga.Y[0] = Qb; ga.Y[1] = Kb; ga.Y[2] = nullptr;
        ga.scale[0] = SC2; ga.scale[1] = 1.f; ga.scale[2] = 1.f;
        ga.Vt = Vtg;
        gemm_qkv<<<dim3(NTOK/128, H_/128, 3), blk, 0, stream>>>(xb, ga, NTOK, H_, H_);
    }

    attn_pv<<<dim3(512), blk, 0, stream>>>(Qb, Kb, Vtg, ctxb, il2);

    {
        FusedArgs fa;
        fa.Qb = Qb; fa.Kb = Kb; fa.il2 = il2; fa.avg_out = avg_out;
        fa.A = ctxb; fa.W = Wob; fa.bias = bo; fa.Y = out;
        colsum_outproj<<<dim3(1024), blk, 0, stream>>>(fa);
    }
}